// Round 5
// baseline (245.744 us; speedup 1.0000x reference)
//
#include <hip/hip_runtime.h>
#include <hip/hip_bf16.h>
#include <hip/hip_fp16.h>

#define IN_DIM 32
#define HID 64
#define H1 2
#define F1 (H1 * HID)   // 128
#define OUT_CH 64
#define NEG_SLOPE 0.2f
#define LN_EPS 1e-5f

#define BSHIFT 9                     // 512 nodes per bucket
#define BMASK ((1 << BSHIFT) - 1)
#define CHUNK 4096                   // edges per block in bucketing pass
#define CAP 10240                    // fixed bucket capacity (mean 8163 + 23 sigma)

typedef __attribute__((ext_vector_type(8))) short short8x;   // 8 bf16 = 4 VGPRs
typedef __attribute__((ext_vector_type(4))) float floatx4;   // MFMA accumulator
typedef __attribute__((ext_vector_type(2))) float floatx2;   // packed-math pair

__device__ __forceinline__ float leaky(float x) {
    return x > 0.f ? x : NEG_SLOPE * x;
}
__device__ __forceinline__ float bf2f(__hip_bfloat16 v) { return __bfloat162float(v); }
__device__ __forceinline__ short f2bs(float v) {
    __hip_bfloat16 t = __float2bfloat16(v);
    return *reinterpret_cast<short*>(&t);
}
// packed fma on a float2 pair: c += a * b (one VOP3P instruction; r1-verified)
__device__ __forceinline__ void pk_fma(floatx2& c, floatx2 a, floatx2 b) {
    asm("v_pk_fma_f32 %0, %1, %2, %0" : "+v"(c) : "v"(a), "v"(b));
}

// ---------------- fused: bucket scatter (fixed-cap) + weight pack ----------------
__global__ __launch_bounds__(256) void k_bucket_pack(const int* __restrict__ src,
                                                     const int* __restrict__ dst,
                                                     int E, int nb, int nchunk,
                                                     int* __restrict__ bfill,
                                                     unsigned int* __restrict__ bedge,
                                                     const float* __restrict__ W1,
                                                     const float* __restrict__ W2,
                                                     const float* __restrict__ att_s,
                                                     const float* __restrict__ att_d,
                                                     __hip_bfloat16* __restrict__ W1t,
                                                     __hip_bfloat16* __restrict__ W2t,
                                                     float* __restrict__ wsd) {
    int t = threadIdx.x;
    if ((int)blockIdx.x >= nchunk) {
        int idx = ((int)blockIdx.x - nchunk) * 256 + t;
        if (idx < IN_DIM * F1) {
            int ch = idx >> 5, k = idx & 31;
            W1t[idx] = __float2bfloat16(W1[k * F1 + ch]);
        }
        if (idx < F1 * OUT_CH) {
            int ch = idx >> 7, k = idx & 127;
            W2t[idx] = __float2bfloat16(W2[k * OUT_CH + ch]);
        }
        if (idx < 128) {
            int v = idx >> 5;              // 0: ws h0, 1: ws h1, 2: wd h0, 3: wd h1
            int k = idx & 31;
            const float* att = (v & 2) ? att_d : att_s;
            int h = v & 1;
            float s = 0.f;
#pragma unroll 8
            for (int c = 0; c < HID; c++)
                s = fmaf(W1[k * F1 + h * HID + c], att[h * HID + c], s);
            wsd[v * 32 + k] = s;
        }
        return;
    }
    __shared__ int h[512];
    __shared__ int gb[512];
    for (int i = t; i < nb; i += 256) h[i] = 0;
    __syncthreads();
    int base = blockIdx.x * CHUNK;
    unsigned int pk[16];
    int rk[16], bk[16];
#pragma unroll
    for (int j = 0; j < 16; j++) {
        int e = base + j * 256 + t;
        if (e < E) {
            int d = dst[e];
            int b = d >> BSHIFT;
            bk[j] = b;
            pk[j] = ((unsigned)src[e] << BSHIFT) | (unsigned)(d & BMASK);
            rk[j] = atomicAdd(&h[b], 1);
        } else bk[j] = -1;
    }
    __syncthreads();
    for (int i = t; i < nb; i += 256)
        gb[i] = h[i] ? atomicAdd(&bfill[i], h[i]) : 0;
    __syncthreads();
#pragma unroll
    for (int j = 0; j < 16; j++)
        if (bk[j] >= 0) {
            int pos = gb[bk[j]] + rk[j];
            if (pos < CAP) bedge[(size_t)bk[j] * CAP + pos] = pk[j];
        }
}

// ---------------- fused: per-bucket CSR build + per-node att1 ----------------
__global__ __launch_bounds__(256) void k_csr_att1(const unsigned int* __restrict__ bedge,
                                                  const int* __restrict__ bfill, int n, int nb,
                                                  int* __restrict__ cnt,
                                                  int* __restrict__ rowptr,
                                                  int* __restrict__ col,
                                                  const float* __restrict__ x,
                                                  const float* __restrict__ wsd,
                                                  __hip_bfloat16* __restrict__ xb16,
                                                  float2* __restrict__ as1,
                                                  float2* __restrict__ ad1) {
    int t = threadIdx.x;
    if ((int)blockIdx.x >= nb) {
        int node = ((int)blockIdx.x - nb) * 256 + t;
        if (node >= n) return;
        const float4* xp = (const float4*)(x + (size_t)node * IN_DIM);
        float4 xr[8];
#pragma unroll
        for (int i = 0; i < 8; i++) xr[i] = xp[i];
        const float* xf = (const float*)xr;
        short8x* xo = (short8x*)(xb16 + (size_t)node * IN_DIM);
#pragma unroll
        for (int i = 0; i < 4; i++) {
            short8x xb;
#pragma unroll
            for (int j = 0; j < 8; j++) xb[j] = f2bs(xf[i * 8 + j]);
            xo[i] = xb;
        }
        float d0 = 0.f, d1 = 0.f, d2 = 0.f, d3 = 0.f;
#pragma unroll
        for (int k = 0; k < 32; k++) {
            float xv = xf[k];
            d0 = fmaf(xv, wsd[k], d0);
            d1 = fmaf(xv, wsd[32 + k], d1);
            d2 = fmaf(xv, wsd[64 + k], d2);
            d3 = fmaf(xv, wsd[96 + k], d3);
        }
        as1[node] = make_float2(d0, d1);
        ad1[node] = make_float2(d2, d3);
        return;
    }
    int b = blockIdx.x;
    __shared__ int lcnt[512];
    __shared__ int lscan[256];
    int nbase = b << BSHIFT;
    lcnt[2 * t] = 0; lcnt[2 * t + 1] = 0;
    __syncthreads();
    int estart = b * CAP;
    int eend = estart + min(bfill[b], CAP);
    for (int e = estart + t; e < eend; e += 256)
        atomicAdd(&lcnt[bedge[e] & BMASK], 1);
    __syncthreads();
    int c0 = lcnt[2 * t], c1 = lcnt[2 * t + 1];
    int s = c0 + c1;
    lscan[t] = s;
    __syncthreads();
    for (int off = 1; off < 256; off <<= 1) {
        int u = (t >= off) ? lscan[t - off] : 0;
        __syncthreads();
        lscan[t] += u;
        __syncthreads();
    }
    int ex = lscan[t] - s;
    int node0 = nbase + 2 * t, node1 = node0 + 1;
    if (node0 < n) { cnt[node0] = c0; rowptr[node0] = estart + ex; }
    if (node1 < n) { cnt[node1] = c1; rowptr[node1] = estart + ex + c0; }
    __syncthreads();
    lcnt[2 * t] = ex;
    lcnt[2 * t + 1] = ex + c0;
    __syncthreads();
    for (int e = estart + t; e < eend; e += 256) {
        unsigned int p = bedge[e];
        int pos = estart + atomicAdd(&lcnt[p & BMASK], 1);
        col[pos] = (int)(p >> BSHIFT);
    }
}

// ---------------- Layer 1 aggregation in x-space (r1-verified version) ----------------
__global__ __launch_bounds__(256) void k_agg1x(const __hip_bfloat16* __restrict__ xb16,
                                               const float2* __restrict__ as1p,
                                               const float2* __restrict__ ad1p,
                                               const int* __restrict__ rowptr,
                                               const int* __restrict__ cnt,
                                               const int* __restrict__ col,
                                               __hip_bfloat16* __restrict__ a, int n) {
    int wave = threadIdx.x >> 6;
    int lane = threadIdx.x & 63;
    int g = lane >> 4;          // group (node within wave)
    int gl = lane & 15;         // lane within group
    int node = blockIdx.x * 16 + wave * 4 + g;
    bool valid = node < n;
    int nc = valid ? node : 0;
    float2 adn = ad1p[nc];
    float2 asn = as1p[nc];
    const __hip_bfloat162* xv2 = (const __hip_bfloat162*)xb16;
    // self loop
    float w0 = __expf(leaky(asn.x + adn.x));
    float w1 = __expf(leaky(asn.y + adn.y));
    __hip_bfloat162 hv = xv2[(size_t)nc * 16 + gl];
    float x0 = bf2f(hv.x), x1 = bf2f(hv.y);
    float a00 = w0 * x0, a01 = w0 * x1;   // head0 ch {2gl, 2gl+1}
    float a10 = w1 * x0, a11 = w1 * x1;   // head1 ch {2gl, 2gl+1}
    float ws0 = w0, ws1 = w1;
    int start = valid ? rowptr[nc] : 0;
    int deg = valid ? cnt[nc] : 0;
    // wave-uniform max degree over the 4 groups
    int mx = deg;
    mx = max(mx, __shfl_xor(mx, 16, 64));
    mx = max(mx, __shfl_xor(mx, 32, 64));
    int gbase = g << 4;
    for (int base = 0; base < mx; base += 16) {
        int m = deg - base;
        int colv = 0; unsigned wvv = 0u;    // wvv=0 => zero contribution for pad slots
        if (gl < m) {
            colv = col[start + base + gl];
            float2 as = as1p[colv];
            float e0 = __expf(leaky(as.x + adn.x));
            float e1 = __expf(leaky(as.y + adn.y));
            wvv = ((unsigned)__half_as_ushort(__float2half(e1)) << 16)
                | (unsigned)__half_as_ushort(__float2half(e0));
        }
        int kend = min(16, mx - base);
        int k = 0;
        for (; k + 8 <= kend; k += 8) {
            int sx[8]; unsigned uw[8];
#pragma unroll
            for (int q = 0; q < 8; q++) {
                sx[q] = __shfl(colv, gbase + k + q);
                uw[q] = __shfl(wvv, gbase + k + q);
            }
            __hip_bfloat162 gx[8];
#pragma unroll
            for (int q = 0; q < 8; q++) gx[q] = xv2[(size_t)sx[q] * 16 + gl];
#pragma unroll
            for (int q = 0; q < 8; q++) {
                float ww0 = __half2float(__ushort_as_half((unsigned short)(uw[q] & 0xffffu)));
                float ww1 = __half2float(__ushort_as_half((unsigned short)(uw[q] >> 16)));
                float gx0 = bf2f(gx[q].x), gx1 = bf2f(gx[q].y);
                a00 = fmaf(ww0, gx0, a00); a01 = fmaf(ww0, gx1, a01);
                a10 = fmaf(ww1, gx0, a10); a11 = fmaf(ww1, gx1, a11);
                ws0 += ww0; ws1 += ww1;
            }
        }
        for (; k < kend; k++) {
            int s = __shfl(colv, gbase + k);
            unsigned u = __shfl(wvv, gbase + k);
            __hip_bfloat162 gxx = xv2[(size_t)s * 16 + gl];
            float ww0 = __half2float(__ushort_as_half((unsigned short)(u & 0xffffu)));
            float ww1 = __half2float(__ushort_as_half((unsigned short)(u >> 16)));
            float gx0 = bf2f(gxx.x), gx1 = bf2f(gxx.y);
            a00 = fmaf(ww0, gx0, a00); a01 = fmaf(ww0, gx1, a01);
            a10 = fmaf(ww1, gx0, a10); a11 = fmaf(ww1, gx1, a11);
            ws0 += ww0; ws1 += ww1;
        }
    }
    if (valid) {
        float inv0 = 1.f / (ws0 + 1e-16f);
        float inv1 = 1.f / (ws1 + 1e-16f);
        __hip_bfloat162* ao = (__hip_bfloat162*)(a + (size_t)node * 64);
        __hip_bfloat162 o0, o1;
        o0.x = __float2bfloat16(a00 * inv0); o0.y = __float2bfloat16(a01 * inv0);
        o1.x = __float2bfloat16(a10 * inv1); o1.y = __float2bfloat16(a11 * inv1);
        ao[gl] = o0;        // head0 ch {2gl,2gl+1}
        ao[16 + gl] = o1;   // head1 ch {2gl,2gl+1}
    }
}

// ---------------- fused: a @ W1 + LN + ReLU -> LDS -> @ W2 + att coefs ----------------
__global__ __launch_bounds__(256) void k_ln1node2(const __hip_bfloat16* __restrict__ a,
                                                  const __hip_bfloat16* __restrict__ W1t,
                                                  const float* __restrict__ bias1,
                                                  const float* __restrict__ gamma,
                                                  const float* __restrict__ beta,
                                                  const __hip_bfloat16* __restrict__ W2t,
                                                  const float* __restrict__ att_s2,
                                                  const float* __restrict__ att_d2,
                                                  __hip_bfloat16* __restrict__ h2b,
                                                  float* __restrict__ as2,
                                                  float* __restrict__ ad2, int n) {
    __shared__ __hip_bfloat16 hs[64][136];   // 64 nodes x 128 ch (+8 pad), 17.4 KB
    int wave = threadIdx.x >> 6;
    int lane = threadIdx.x & 63;
    int row16 = lane & 15;
    int quad = lane >> 4;
    int node0 = blockIdx.x * 64 + wave * 16;

    // ---- phase 1: ln1 ----
    {
        short8x bfr[8];
#pragma unroll
        for (int nt = 0; nt < 8; nt++)
            bfr[nt] = *(const short8x*)(W1t + (nt * 16 + row16) * IN_DIM + quad * 8);

        int arow = node0 + row16;
        if (arow >= n) arow = n - 1;
        const __hip_bfloat16* ap = a + (size_t)arow * 64 + quad * 8;
        short8x af0 = *(const short8x*)ap;          // head0 channels (k 0..31)
        short8x af1 = *(const short8x*)(ap + 32);   // head1 channels (k 32..63)

        floatx4 acc[8];
#pragma unroll
        for (int nt = 0; nt < 8; nt++) acc[nt] = (floatx4){0.f, 0.f, 0.f, 0.f};
#pragma unroll
        for (int nt = 0; nt < 8; nt++)
            acc[nt] = __builtin_amdgcn_mfma_f32_16x16x32_bf16(nt < 4 ? af0 : af1, bfr[nt],
                                                              acc[nt], 0, 0, 0);

        float bv[8], gv[8], btv[8];
#pragma unroll
        for (int nt = 0; nt < 8; nt++) {
            int ch = nt * 16 + row16;
            bv[nt] = bias1[ch];
            gv[nt] = gamma[ch];
            btv[nt] = beta[ch];
        }
#pragma unroll
        for (int rr = 0; rr < 4; rr++) {
            int node = node0 + quad * 4 + rr;
            float v[8];
            float sum = 0.f, sq = 0.f;
#pragma unroll
            for (int nt = 0; nt < 8; nt++) {
                v[nt] = acc[nt][rr] + bv[nt];
                sum += v[nt];
                sq += v[nt] * v[nt];
            }
#pragma unroll
            for (int off = 1; off < 16; off <<= 1) {
                sum += __shfl_xor(sum, off, 64);
                sq += __shfl_xor(sq, off, 64);
            }
            float mu = sum * (1.f / 128.f);
            float var = sq * (1.f / 128.f) - mu * mu;
            float r = rsqrtf(var + LN_EPS);
            if (node < n) {
                int lr = wave * 16 + quad * 4 + rr;
#pragma unroll
                for (int nt = 0; nt < 8; nt++) {
                    float o = (v[nt] - mu) * r * gv[nt] + btv[nt];
                    hs[lr][nt * 16 + row16] = __float2bfloat16(fmaxf(o, 0.f));
                }
            }
        }
    }
    __syncthreads();

    // ---- phase 2: node2 ----
    short8x bfr2[4][4];
#pragma unroll
    for (int nt = 0; nt < 4; nt++) {
        const __hip_bfloat16* wrow = W2t + (nt * 16 + row16) * F1 + quad * 8;
#pragma unroll
        for (int kc = 0; kc < 4; kc++)
            bfr2[kc][nt] = *(const short8x*)(wrow + kc * 32);
    }

    floatx4 acc2[4];
#pragma unroll
    for (int nt = 0; nt < 4; nt++) acc2[nt] = (floatx4){0.f, 0.f, 0.f, 0.f};

    int lrow = wave * 16 + row16;   // rows beyond n hold garbage; outputs are guarded
#pragma unroll
    for (int kc = 0; kc < 4; kc++) {
        short8x af = *(const short8x*)&hs[lrow][quad * 8 + kc * 32];
#pragma unroll
        for (int nt = 0; nt < 4; nt++)
            acc2[nt] = __builtin_amdgcn_mfma_f32_16x16x32_bf16(af, bfr2[kc][nt], acc2[nt],
                                                               0, 0, 0);
    }

    float asv[4], adv[4];
#pragma unroll
    for (int nt = 0; nt < 4; nt++) {
        asv[nt] = att_s2[nt * 16 + row16];
        adv[nt] = att_d2[nt * 16 + row16];
    }
#pragma unroll
    for (int rr = 0; rr < 4; rr++) {
        int node = node0 + quad * 4 + rr;
        float ps = 0.f, pd = 0.f;
#pragma unroll
        for (int nt = 0; nt < 4; nt++) {
            float v = acc2[nt][rr];
            if (node < n) h2b[(size_t)node * OUT_CH + nt * 16 + row16] = __float2bfloat16(v);
            ps = fmaf(v, asv[nt], ps);
            pd = fmaf(v, adv[nt], pd);
        }
#pragma unroll
        for (int off = 1; off < 16; off <<= 1) {
            ps += __shfl_xor(ps, off, 64);
            pd += __shfl_xor(pd, off, 64);
        }
        if (row16 == 0 && node < n) { as2[node] = ps; ad2[node] = pd; }
    }
}

// ---------------- Layer 2 aggregation: 4-edge quarter scheme ----------------
// 1 node/wave. Lane c=lane&15 owns channels {4c..4c+3} (uint2 = 2 bf16x2); quarter
// q=lane>>4 takes edge 4p+q. Per 4 edges: 2 bpermute + 1 8B-gather instr (each row
// read coalesced by 16 lanes) + 2 pk_fma per lane. Chunk weight-sum reduced once per
// 64-edge chunk via butterfly (replaces per-edge wsum adds). Quarter partials
// combined with 2 shfl_xor steps; lanes 0-15 write one coalesced float4 row.
__global__ __launch_bounds__(256) void k_agg2(const __hip_bfloat16* __restrict__ h2b,
                                              const float* __restrict__ as2,
                                              const float* __restrict__ ad2,
                                              const int* __restrict__ rowptr,
                                              const int* __restrict__ cnt,
                                              const int* __restrict__ col,
                                              const float* __restrict__ bias2,
                                              float* __restrict__ out, int n) {
    int node = blockIdx.x * 4 + (threadIdx.x >> 6);
    int lane = threadIdx.x & 63;
    if (node >= n) return;
    int c = lane & 15;            // channel group: ch 4c..4c+3
    int quarter = lane >> 4;      // edge slot within a 4-edge group
    const unsigned* h2u = (const unsigned*)h2b;   // bf16x2 words, 32 per row
    float adn = ad2[node];
    float wself = __expf(leaky(as2[node] + adn));
    floatx2 accA = {0.f, 0.f}, accB = {0.f, 0.f};
    if (quarter == 0) {           // self loop seeded on quarter 0 only
        uint2 su = *(const uint2*)(h2u + (size_t)node * 32 + c * 2);
        accA.x = wself * __uint_as_float(su.x << 16);
        accA.y = wself * __uint_as_float(su.x & 0xffff0000u);
        accB.x = wself * __uint_as_float(su.y << 16);
        accB.y = wself * __uint_as_float(su.y & 0xffff0000u);
    }
    float wsum = wself;           // uniform across lanes
    int start = rowptr[node], deg = cnt[node];
    for (int base = 0; base < deg; base += 64) {
        int m = min(64, deg - base);
        int colv = 0; float wvv = 0.f;    // wvv=0 for pad slots => zero contribution
        if (lane < m) {
            colv = col[start + base + lane];
            wvv = __expf(leaky(as2[colv] + adn));
        }
        // chunk weight sum once (butterfly over all 64 lanes)
        float r = wvv;
#pragma unroll
        for (int off = 1; off < 64; off <<= 1) r += __shfl_xor(r, off, 64);
        wsum += r;
        int P = (m + 3) >> 2;             // 4-edge groups in this chunk
        int p = 0;
        for (; p + 4 <= P; p += 4) {
            int sx[4]; float wx[4];
#pragma unroll
            for (int u = 0; u < 4; u++) {
                int idx = 4 * (p + u) + quarter;   // <= 63 always
                sx[u] = __shfl(colv, idx);
                wx[u] = __shfl(wvv, idx);
            }
            uint2 gu[4];
#pragma unroll
            for (int u = 0; u < 4; u++)
                gu[u] = *(const uint2*)(h2u + (size_t)sx[u] * 32 + c * 2);
#pragma unroll
            for (int u = 0; u < 4; u++) {
                floatx2 wp = {wx[u], wx[u]};
                floatx2 g0 = {__uint_as_float(gu[u].x << 16),
                              __uint_as_float(gu[u].x & 0xffff0000u)};
                floatx2 g1 = {__uint_as_float(gu[u].y << 16),
                              __uint_as_float(gu[u].y & 0xffff0000u)};
                pk_fma(accA, wp, g0);
                pk_fma(accB, wp, g1);
            }
        }
        for (; p < P; p++) {
            int idx = 4 * p + quarter;
            int s = __shfl(colv, idx);
            float wk = __shfl(wvv, idx);
            uint2 u2 = *(const uint2*)(h2u + (size_t)s * 32 + c * 2);
            floatx2 wp = {wk, wk};
            floatx2 g0 = {__uint_as_float(u2.x << 16),
                          __uint_as_float(u2.x & 0xffff0000u)};
            floatx2 g1 = {__uint_as_float(u2.y << 16),
                          __uint_as_float(u2.y & 0xffff0000u)};
            pk_fma(accA, wp, g0);
            pk_fma(accB, wp, g1);
        }
    }
    // combine quarter partials
#pragma unroll
    for (int off = 16; off <= 32; off <<= 1) {
        accA.x += __shfl_xor(accA.x, off, 64);
        accA.y += __shfl_xor(accA.y, off, 64);
        accB.x += __shfl_xor(accB.x, off, 64);
        accB.y += __shfl_xor(accB.y, off, 64);
    }
    float inv = 1.f / (wsum + 1e-16f);
    if (quarter == 0) {
        float4 bv = ((const float4*)bias2)[c];
        float4 ov;
        ov.x = accA.x * inv + bv.x;
        ov.y = accA.y * inv + bv.y;
        ov.z = accB.x * inv + bv.z;
        ov.w = accB.y * inv + bv.w;
        ((float4*)out)[(size_t)node * 16 + c] = ov;
    }
}

extern "C" void kernel_launch(void* const* d_in, const int* in_sizes, int n_in,
                              void* d_out, int out_size, void* d_ws, size_t ws_size,
                              hipStream_t stream) {
    const float* x        = (const float*)d_in[0];
    const int*   eidx     = (const int*)d_in[1];
    const float* W1       = (const float*)d_in[2];
    const float* att_src1 = (const float*)d_in[3];
    const float* att_dst1 = (const float*)d_in[4];
    const float* bias1    = (const float*)d_in[5];
    const float* gamma    = (const float*)d_in[6];
    const float* beta     = (const float*)d_in[7];
    const float* W2       = (const float*)d_in[8];
    const float* att_src2 = (const float*)d_in[9];
    const float* att_dst2 = (const float*)d_in[10];
    const float* bias2    = (const float*)d_in[11];
    float* out = (float*)d_out;

    const int N = in_sizes[0] / IN_DIM;      // 100000
    const int E = in_sizes[1] / 2;           // 1600000
    const int* src = eidx;
    const int* dst = eidx + E;
    const int nb = (N + BMASK) >> BSHIFT;    // 196 buckets

    char* w = (char*)d_ws;
    __hip_bfloat16* xb16  = (__hip_bfloat16*)w;  w += (size_t)N * IN_DIM * 2;   // 6.4 MB
    __hip_bfloat16* a     = (__hip_bfloat16*)w;  w += (size_t)N * 64 * 2;       // 12.8 MB
    __hip_bfloat16* h2b   = (__hip_bfloat16*)w;  w += (size_t)N * OUT_CH * 2;   // 12.8 MB
    __hip_bfloat16* W1t   = (__hip_bfloat16*)w;  w += IN_DIM * F1 * 2;
    __hip_bfloat16* W2t   = (__hip_bfloat16*)w;  w += F1 * OUT_CH * 2;
    float* wsd = (float*)w; w += 128 * 4;
    float* as1 = (float*)w; w += (size_t)N * 2 * 4;
    float* ad1 = (float*)w; w += (size_t)N * 2 * 4;
    float* as2 = (float*)w; w += (size_t)N * 4;
    float* ad2 = (float*)w; w += (size_t)N * 4;
    int* cnt    = (int*)w; w += (size_t)N * 4;
    int* rowptr = (int*)w; w += (size_t)N * 4;
    int* bfill  = (int*)w; w += 512 * 4;
    int* col    = (int*)w; w += (size_t)nb * CAP * 4;   // 8.0 MB (CAP-padded)
    unsigned int* bedge = (unsigned int*)w; w += (size_t)nb * CAP * 4;

    const int nchunk = (E + CHUNK - 1) / CHUNK;   // 391

    hipMemsetAsync(bfill, 0, 512 * 4, stream);
    k_bucket_pack<<<nchunk + 32, 256, 0, stream>>>(src, dst, E, nb, nchunk, bfill, bedge,
                                                   W1, W2, att_src1, att_dst1,
                                                   W1t, W2t, wsd);
    k_csr_att1<<<nb + (N + 255) / 256, 256, 0, stream>>>(bedge, bfill, N, nb,
                                                         cnt, rowptr, col,
                                                         x, wsd, xb16,
                                                         (float2*)as1, (float2*)ad1);
    k_agg1x<<<(N + 15) / 16, 256, 0, stream>>>(xb16, (const float2*)as1, (const float2*)ad1,
                                               rowptr, cnt, col, a, N);
    k_ln1node2<<<(N + 63) / 64, 256, 0, stream>>>(a, W1t, bias1, gamma, beta,
                                                  W2t, att_src2, att_dst2,
                                                  h2b, as2, ad2, N);
    k_agg2<<<(N + 3) / 4, 256, 0, stream>>>(h2b, as2, ad2,
                                            rowptr, cnt, col, bias2, out, N);
}

// Round 6
// 226.306 us; speedup vs baseline: 1.0859x; 1.0859x over previous
//
#include <hip/hip_runtime.h>
#include <hip/hip_bf16.h>
#include <hip/hip_fp16.h>

#define IN_DIM 32
#define HID 64
#define H1 2
#define F1 (H1 * HID)   // 128
#define OUT_CH 64
#define NEG_SLOPE 0.2f
#define LN_EPS 1e-5f

#define BSHIFT 9                     // 512 nodes per bucket
#define BMASK ((1 << BSHIFT) - 1)
#define CHUNK 4096                   // edges per block in bucketing pass
#define CAP 10240                    // fixed bucket capacity (mean 8163 + 23 sigma)

typedef __attribute__((ext_vector_type(8))) short short8x;   // 8 bf16 = 4 VGPRs
typedef __attribute__((ext_vector_type(4))) float floatx4;   // MFMA accumulator
typedef __attribute__((ext_vector_type(2))) float floatx2;   // packed-math pair

__device__ __forceinline__ float leaky(float x) {
    return x > 0.f ? x : NEG_SLOPE * x;
}
__device__ __forceinline__ float bf2f(__hip_bfloat16 v) { return __bfloat162float(v); }
__device__ __forceinline__ short f2bs(float v) {
    __hip_bfloat16 t = __float2bfloat16(v);
    return *reinterpret_cast<short*>(&t);
}
// packed fma on a float2 pair: c += a * b (one VOP3P instruction; r1-verified)
__device__ __forceinline__ void pk_fma(floatx2& c, floatx2 a, floatx2 b) {
    asm("v_pk_fma_f32 %0, %1, %2, %0" : "+v"(c) : "v"(a), "v"(b));
}

// ---------------- fused: bucket scatter (fixed-cap) + weight pack ----------------
__global__ __launch_bounds__(256) void k_bucket_pack(const int* __restrict__ src,
                                                     const int* __restrict__ dst,
                                                     int E, int nb, int nchunk,
                                                     int* __restrict__ bfill,
                                                     unsigned int* __restrict__ bedge,
                                                     const float* __restrict__ W1,
                                                     const float* __restrict__ W2,
                                                     const float* __restrict__ att_s,
                                                     const float* __restrict__ att_d,
                                                     __hip_bfloat16* __restrict__ W1t,
                                                     __hip_bfloat16* __restrict__ W2t,
                                                     float* __restrict__ wsd) {
    int t = threadIdx.x;
    if ((int)blockIdx.x >= nchunk) {
        int idx = ((int)blockIdx.x - nchunk) * 256 + t;
        if (idx < IN_DIM * F1) {
            int ch = idx >> 5, k = idx & 31;
            W1t[idx] = __float2bfloat16(W1[k * F1 + ch]);
        }
        if (idx < F1 * OUT_CH) {
            int ch = idx >> 7, k = idx & 127;
            W2t[idx] = __float2bfloat16(W2[k * OUT_CH + ch]);
        }
        if (idx < 128) {
            int v = idx >> 5;              // 0: ws h0, 1: ws h1, 2: wd h0, 3: wd h1
            int k = idx & 31;
            const float* att = (v & 2) ? att_d : att_s;
            int h = v & 1;
            float s = 0.f;
#pragma unroll 8
            for (int c = 0; c < HID; c++)
                s = fmaf(W1[k * F1 + h * HID + c], att[h * HID + c], s);
            wsd[v * 32 + k] = s;
        }
        return;
    }
    __shared__ int h[512];
    __shared__ int gb[512];
    for (int i = t; i < nb; i += 256) h[i] = 0;
    __syncthreads();
    int base = blockIdx.x * CHUNK;
    unsigned int pk[16];
    int rk[16], bk[16];
#pragma unroll
    for (int j = 0; j < 16; j++) {
        int e = base + j * 256 + t;
        if (e < E) {
            int d = dst[e];
            int b = d >> BSHIFT;
            bk[j] = b;
            pk[j] = ((unsigned)src[e] << BSHIFT) | (unsigned)(d & BMASK);
            rk[j] = atomicAdd(&h[b], 1);
        } else bk[j] = -1;
    }
    __syncthreads();
    for (int i = t; i < nb; i += 256)
        gb[i] = h[i] ? atomicAdd(&bfill[i], h[i]) : 0;
    __syncthreads();
#pragma unroll
    for (int j = 0; j < 16; j++)
        if (bk[j] >= 0) {
            int pos = gb[bk[j]] + rk[j];
            if (pos < CAP) bedge[(size_t)bk[j] * CAP + pos] = pk[j];
        }
}

// ---------------- fused: per-bucket CSR build + per-node att1 ----------------
__global__ __launch_bounds__(256) void k_csr_att1(const unsigned int* __restrict__ bedge,
                                                  const int* __restrict__ bfill, int n, int nb,
                                                  int* __restrict__ cnt,
                                                  int* __restrict__ rowptr,
                                                  int* __restrict__ col,
                                                  const float* __restrict__ x,
                                                  const float* __restrict__ wsd,
                                                  __hip_bfloat16* __restrict__ xb16,
                                                  float2* __restrict__ as1,
                                                  float2* __restrict__ ad1) {
    int t = threadIdx.x;
    if ((int)blockIdx.x >= nb) {
        int node = ((int)blockIdx.x - nb) * 256 + t;
        if (node >= n) return;
        const float4* xp = (const float4*)(x + (size_t)node * IN_DIM);
        float4 xr[8];
#pragma unroll
        for (int i = 0; i < 8; i++) xr[i] = xp[i];
        const float* xf = (const float*)xr;
        short8x* xo = (short8x*)(xb16 + (size_t)node * IN_DIM);
#pragma unroll
        for (int i = 0; i < 4; i++) {
            short8x xb;
#pragma unroll
            for (int j = 0; j < 8; j++) xb[j] = f2bs(xf[i * 8 + j]);
            xo[i] = xb;
        }
        float d0 = 0.f, d1 = 0.f, d2 = 0.f, d3 = 0.f;
#pragma unroll
        for (int k = 0; k < 32; k++) {
            float xv = xf[k];
            d0 = fmaf(xv, wsd[k], d0);
            d1 = fmaf(xv, wsd[32 + k], d1);
            d2 = fmaf(xv, wsd[64 + k], d2);
            d3 = fmaf(xv, wsd[96 + k], d3);
        }
        as1[node] = make_float2(d0, d1);
        ad1[node] = make_float2(d2, d3);
        return;
    }
    int b = blockIdx.x;
    __shared__ int lcnt[512];
    __shared__ int lscan[256];
    int nbase = b << BSHIFT;
    lcnt[2 * t] = 0; lcnt[2 * t + 1] = 0;
    __syncthreads();
    int estart = b * CAP;
    int eend = estart + min(bfill[b], CAP);
    for (int e = estart + t; e < eend; e += 256)
        atomicAdd(&lcnt[bedge[e] & BMASK], 1);
    __syncthreads();
    int c0 = lcnt[2 * t], c1 = lcnt[2 * t + 1];
    int s = c0 + c1;
    lscan[t] = s;
    __syncthreads();
    for (int off = 1; off < 256; off <<= 1) {
        int u = (t >= off) ? lscan[t - off] : 0;
        __syncthreads();
        lscan[t] += u;
        __syncthreads();
    }
    int ex = lscan[t] - s;
    int node0 = nbase + 2 * t, node1 = node0 + 1;
    if (node0 < n) { cnt[node0] = c0; rowptr[node0] = estart + ex; }
    if (node1 < n) { cnt[node1] = c1; rowptr[node1] = estart + ex + c0; }
    __syncthreads();
    lcnt[2 * t] = ex;
    lcnt[2 * t + 1] = ex + c0;
    __syncthreads();
    for (int e = estart + t; e < eend; e += 256) {
        unsigned int p = bedge[e];
        int pos = estart + atomicAdd(&lcnt[p & BMASK], 1);
        col[pos] = (int)(p >> BSHIFT);
    }
}

// ---------------- Layer 1 aggregation in x-space (r1-verified version) ----------------
__global__ __launch_bounds__(256) void k_agg1x(const __hip_bfloat16* __restrict__ xb16,
                                               const float2* __restrict__ as1p,
                                               const float2* __restrict__ ad1p,
                                               const int* __restrict__ rowptr,
                                               const int* __restrict__ cnt,
                                               const int* __restrict__ col,
                                               __hip_bfloat16* __restrict__ a, int n) {
    int wave = threadIdx.x >> 6;
    int lane = threadIdx.x & 63;
    int g = lane >> 4;          // group (node within wave)
    int gl = lane & 15;         // lane within group
    int node = blockIdx.x * 16 + wave * 4 + g;
    bool valid = node < n;
    int nc = valid ? node : 0;
    float2 adn = ad1p[nc];
    float2 asn = as1p[nc];
    const __hip_bfloat162* xv2 = (const __hip_bfloat162*)xb16;
    // self loop
    float w0 = __expf(leaky(asn.x + adn.x));
    float w1 = __expf(leaky(asn.y + adn.y));
    __hip_bfloat162 hv = xv2[(size_t)nc * 16 + gl];
    float x0 = bf2f(hv.x), x1 = bf2f(hv.y);
    float a00 = w0 * x0, a01 = w0 * x1;   // head0 ch {2gl, 2gl+1}
    float a10 = w1 * x0, a11 = w1 * x1;   // head1 ch {2gl, 2gl+1}
    float ws0 = w0, ws1 = w1;
    int start = valid ? rowptr[nc] : 0;
    int deg = valid ? cnt[nc] : 0;
    // wave-uniform max degree over the 4 groups
    int mx = deg;
    mx = max(mx, __shfl_xor(mx, 16, 64));
    mx = max(mx, __shfl_xor(mx, 32, 64));
    int gbase = g << 4;
    for (int base = 0; base < mx; base += 16) {
        int m = deg - base;
        int colv = 0; unsigned wvv = 0u;    // wvv=0 => zero contribution for pad slots
        if (gl < m) {
            colv = col[start + base + gl];
            float2 as = as1p[colv];
            float e0 = __expf(leaky(as.x + adn.x));
            float e1 = __expf(leaky(as.y + adn.y));
            wvv = ((unsigned)__half_as_ushort(__float2half(e1)) << 16)
                | (unsigned)__half_as_ushort(__float2half(e0));
        }
        int kend = min(16, mx - base);
        int k = 0;
        for (; k + 8 <= kend; k += 8) {
            int sx[8]; unsigned uw[8];
#pragma unroll
            for (int q = 0; q < 8; q++) {
                sx[q] = __shfl(colv, gbase + k + q);
                uw[q] = __shfl(wvv, gbase + k + q);
            }
            __hip_bfloat162 gx[8];
#pragma unroll
            for (int q = 0; q < 8; q++) gx[q] = xv2[(size_t)sx[q] * 16 + gl];
#pragma unroll
            for (int q = 0; q < 8; q++) {
                float ww0 = __half2float(__ushort_as_half((unsigned short)(uw[q] & 0xffffu)));
                float ww1 = __half2float(__ushort_as_half((unsigned short)(uw[q] >> 16)));
                float gx0 = bf2f(gx[q].x), gx1 = bf2f(gx[q].y);
                a00 = fmaf(ww0, gx0, a00); a01 = fmaf(ww0, gx1, a01);
                a10 = fmaf(ww1, gx0, a10); a11 = fmaf(ww1, gx1, a11);
                ws0 += ww0; ws1 += ww1;
            }
        }
        for (; k < kend; k++) {
            int s = __shfl(colv, gbase + k);
            unsigned u = __shfl(wvv, gbase + k);
            __hip_bfloat162 gxx = xv2[(size_t)s * 16 + gl];
            float ww0 = __half2float(__ushort_as_half((unsigned short)(u & 0xffffu)));
            float ww1 = __half2float(__ushort_as_half((unsigned short)(u >> 16)));
            float gx0 = bf2f(gxx.x), gx1 = bf2f(gxx.y);
            a00 = fmaf(ww0, gx0, a00); a01 = fmaf(ww0, gx1, a01);
            a10 = fmaf(ww1, gx0, a10); a11 = fmaf(ww1, gx1, a11);
            ws0 += ww0; ws1 += ww1;
        }
    }
    if (valid) {
        float inv0 = 1.f / (ws0 + 1e-16f);
        float inv1 = 1.f / (ws1 + 1e-16f);
        __hip_bfloat162* ao = (__hip_bfloat162*)(a + (size_t)node * 64);
        __hip_bfloat162 o0, o1;
        o0.x = __float2bfloat16(a00 * inv0); o0.y = __float2bfloat16(a01 * inv0);
        o1.x = __float2bfloat16(a10 * inv1); o1.y = __float2bfloat16(a11 * inv1);
        ao[gl] = o0;        // head0 ch {2gl,2gl+1}
        ao[16 + gl] = o1;   // head1 ch {2gl,2gl+1}
    }
}

// ---------------- fused: a @ W1 + LN + ReLU -> LDS -> @ W2 + att coefs ----------------
__global__ __launch_bounds__(256) void k_ln1node2(const __hip_bfloat16* __restrict__ a,
                                                  const __hip_bfloat16* __restrict__ W1t,
                                                  const float* __restrict__ bias1,
                                                  const float* __restrict__ gamma,
                                                  const float* __restrict__ beta,
                                                  const __hip_bfloat16* __restrict__ W2t,
                                                  const float* __restrict__ att_s2,
                                                  const float* __restrict__ att_d2,
                                                  __hip_bfloat16* __restrict__ h2b,
                                                  float* __restrict__ as2,
                                                  float* __restrict__ ad2, int n) {
    __shared__ __hip_bfloat16 hs[64][136];   // 64 nodes x 128 ch (+8 pad), 17.4 KB
    int wave = threadIdx.x >> 6;
    int lane = threadIdx.x & 63;
    int row16 = lane & 15;
    int quad = lane >> 4;
    int node0 = blockIdx.x * 64 + wave * 16;

    // ---- phase 1: ln1 ----
    {
        short8x bfr[8];
#pragma unroll
        for (int nt = 0; nt < 8; nt++)
            bfr[nt] = *(const short8x*)(W1t + (nt * 16 + row16) * IN_DIM + quad * 8);

        int arow = node0 + row16;
        if (arow >= n) arow = n - 1;
        const __hip_bfloat16* ap = a + (size_t)arow * 64 + quad * 8;
        short8x af0 = *(const short8x*)ap;          // head0 channels (k 0..31)
        short8x af1 = *(const short8x*)(ap + 32);   // head1 channels (k 32..63)

        floatx4 acc[8];
#pragma unroll
        for (int nt = 0; nt < 8; nt++) acc[nt] = (floatx4){0.f, 0.f, 0.f, 0.f};
#pragma unroll
        for (int nt = 0; nt < 8; nt++)
            acc[nt] = __builtin_amdgcn_mfma_f32_16x16x32_bf16(nt < 4 ? af0 : af1, bfr[nt],
                                                              acc[nt], 0, 0, 0);

        float bv[8], gv[8], btv[8];
#pragma unroll
        for (int nt = 0; nt < 8; nt++) {
            int ch = nt * 16 + row16;
            bv[nt] = bias1[ch];
            gv[nt] = gamma[ch];
            btv[nt] = beta[ch];
        }
#pragma unroll
        for (int rr = 0; rr < 4; rr++) {
            int node = node0 + quad * 4 + rr;
            float v[8];
            float sum = 0.f, sq = 0.f;
#pragma unroll
            for (int nt = 0; nt < 8; nt++) {
                v[nt] = acc[nt][rr] + bv[nt];
                sum += v[nt];
                sq += v[nt] * v[nt];
            }
#pragma unroll
            for (int off = 1; off < 16; off <<= 1) {
                sum += __shfl_xor(sum, off, 64);
                sq += __shfl_xor(sq, off, 64);
            }
            float mu = sum * (1.f / 128.f);
            float var = sq * (1.f / 128.f) - mu * mu;
            float r = rsqrtf(var + LN_EPS);
            if (node < n) {
                int lr = wave * 16 + quad * 4 + rr;
#pragma unroll
                for (int nt = 0; nt < 8; nt++) {
                    float o = (v[nt] - mu) * r * gv[nt] + btv[nt];
                    hs[lr][nt * 16 + row16] = __float2bfloat16(fmaxf(o, 0.f));
                }
            }
        }
    }
    __syncthreads();

    // ---- phase 2: node2 ----
    short8x bfr2[4][4];
#pragma unroll
    for (int nt = 0; nt < 4; nt++) {
        const __hip_bfloat16* wrow = W2t + (nt * 16 + row16) * F1 + quad * 8;
#pragma unroll
        for (int kc = 0; kc < 4; kc++)
            bfr2[kc][nt] = *(const short8x*)(wrow + kc * 32);
    }

    floatx4 acc2[4];
#pragma unroll
    for (int nt = 0; nt < 4; nt++) acc2[nt] = (floatx4){0.f, 0.f, 0.f, 0.f};

    int lrow = wave * 16 + row16;   // rows beyond n hold garbage; outputs are guarded
#pragma unroll
    for (int kc = 0; kc < 4; kc++) {
        short8x af = *(const short8x*)&hs[lrow][quad * 8 + kc * 32];
#pragma unroll
        for (int nt = 0; nt < 4; nt++)
            acc2[nt] = __builtin_amdgcn_mfma_f32_16x16x32_bf16(af, bfr2[kc][nt], acc2[nt],
                                                               0, 0, 0);
    }

    float asv[4], adv[4];
#pragma unroll
    for (int nt = 0; nt < 4; nt++) {
        asv[nt] = att_s2[nt * 16 + row16];
        adv[nt] = att_d2[nt * 16 + row16];
    }
#pragma unroll
    for (int rr = 0; rr < 4; rr++) {
        int node = node0 + quad * 4 + rr;
        float ps = 0.f, pd = 0.f;
#pragma unroll
        for (int nt = 0; nt < 4; nt++) {
            float v = acc2[nt][rr];
            if (node < n) h2b[(size_t)node * OUT_CH + nt * 16 + row16] = __float2bfloat16(v);
            ps = fmaf(v, asv[nt], ps);
            pd = fmaf(v, adv[nt], pd);
        }
#pragma unroll
        for (int off = 1; off < 16; off <<= 1) {
            ps += __shfl_xor(ps, off, 64);
            pd += __shfl_xor(pd, off, 64);
        }
        if (row16 == 0 && node < n) { as2[node] = ps; ad2[node] = pd; }
    }
}

// ---------------- Layer 2 aggregation: 4 nodes/wave, 16 lanes/node ----------------
// Mirror of k_agg1x's structure (the verified big win): group g=lane>>4 owns node
// blockIdx*16+wave*4+g; lane gl=lane&15 owns channels {4gl..4gl+3} (uint2 = 2 bf16x2).
// One gather instr covers 4 rows (4 edges, one per node); 4 independent per-node
// latency chains per wave; prologue/epilogue amortized 4x; no cross-lane epilogue
// reduce (each lane holds final channels -> coalesced float4 write). wsum reduced
// once per 16-edge chunk via a 4-step group butterfly.
__global__ __launch_bounds__(256) void k_agg2(const __hip_bfloat16* __restrict__ h2b,
                                              const float* __restrict__ as2,
                                              const float* __restrict__ ad2,
                                              const int* __restrict__ rowptr,
                                              const int* __restrict__ cnt,
                                              const int* __restrict__ col,
                                              const float* __restrict__ bias2,
                                              float* __restrict__ out, int n) {
    int wave = threadIdx.x >> 6;
    int lane = threadIdx.x & 63;
    int g = lane >> 4;          // node within wave
    int gl = lane & 15;         // channel group: ch 4gl..4gl+3
    int node = blockIdx.x * 16 + wave * 4 + g;
    bool valid = node < n;
    int nc = valid ? node : 0;
    const unsigned* h2u = (const unsigned*)h2b;   // bf16x2 words, 32 per row
    float adn = ad2[nc];
    float wself = __expf(leaky(as2[nc] + adn));
    // self loop
    uint2 su = *(const uint2*)(h2u + (size_t)nc * 32 + gl * 2);
    floatx2 wsp = {wself, wself};
    floatx2 accA = {wself * __uint_as_float(su.x << 16),
                    wself * __uint_as_float(su.x & 0xffff0000u)};
    floatx2 accB = {wself * __uint_as_float(su.y << 16),
                    wself * __uint_as_float(su.y & 0xffff0000u)};
    float wsum = wself;
    int start = valid ? rowptr[nc] : 0;
    int deg = valid ? cnt[nc] : 0;
    // wave-uniform max degree over the 4 groups
    int mx = deg;
    mx = max(mx, __shfl_xor(mx, 16, 64));
    mx = max(mx, __shfl_xor(mx, 32, 64));
    int gbase = g << 4;
    for (int base = 0; base < mx; base += 16) {
        int m = deg - base;
        int colv = 0; float wvv = 0.f;      // wvv=0 => zero contribution for pad slots
        if (gl < m) {
            colv = col[start + base + gl];
            wvv = __expf(leaky(as2[colv] + adn));
        }
        // chunk weight sum (butterfly within the 16-lane group)
        float r = wvv;
#pragma unroll
        for (int off = 1; off < 16; off <<= 1) r += __shfl_xor(r, off, 64);
        wsum += r;
        int kend = min(16, mx - base);
        int k = 0;
        for (; k + 8 <= kend; k += 8) {
            int sx[8]; float wx[8];
#pragma unroll
            for (int q = 0; q < 8; q++) {
                sx[q] = __shfl(colv, gbase + k + q);
                wx[q] = __shfl(wvv, gbase + k + q);
            }
            uint2 gu[8];
#pragma unroll
            for (int q = 0; q < 8; q++)
                gu[q] = *(const uint2*)(h2u + (size_t)sx[q] * 32 + gl * 2);
#pragma unroll
            for (int q = 0; q < 8; q++) {
                floatx2 wp = {wx[q], wx[q]};
                floatx2 g0 = {__uint_as_float(gu[q].x << 16),
                              __uint_as_float(gu[q].x & 0xffff0000u)};
                floatx2 g1 = {__uint_as_float(gu[q].y << 16),
                              __uint_as_float(gu[q].y & 0xffff0000u)};
                pk_fma(accA, wp, g0);
                pk_fma(accB, wp, g1);
            }
        }
        for (; k < kend; k++) {
            int s = __shfl(colv, gbase + k);
            float wk = __shfl(wvv, gbase + k);
            uint2 u2 = *(const uint2*)(h2u + (size_t)s * 32 + gl * 2);
            floatx2 wp = {wk, wk};
            floatx2 g0 = {__uint_as_float(u2.x << 16),
                          __uint_as_float(u2.x & 0xffff0000u)};
            floatx2 g1 = {__uint_as_float(u2.y << 16),
                          __uint_as_float(u2.y & 0xffff0000u)};
            pk_fma(accA, wp, g0);
            pk_fma(accB, wp, g1);
        }
    }
    if (valid) {
        float inv = 1.f / (wsum + 1e-16f);
        float4 bv = ((const float4*)bias2)[gl];
        float4 ov;
        ov.x = accA.x * inv + bv.x;
        ov.y = accA.y * inv + bv.y;
        ov.z = accB.x * inv + bv.z;
        ov.w = accB.y * inv + bv.w;
        ((float4*)out)[(size_t)node * 16 + gl] = ov;
    }
}

extern "C" void kernel_launch(void* const* d_in, const int* in_sizes, int n_in,
                              void* d_out, int out_size, void* d_ws, size_t ws_size,
                              hipStream_t stream) {
    const float* x        = (const float*)d_in[0];
    const int*   eidx     = (const int*)d_in[1];
    const float* W1       = (const float*)d_in[2];
    const float* att_src1 = (const float*)d_in[3];
    const float* att_dst1 = (const float*)d_in[4];
    const float* bias1    = (const float*)d_in[5];
    const float* gamma    = (const float*)d_in[6];
    const float* beta     = (const float*)d_in[7];
    const float* W2       = (const float*)d_in[8];
    const float* att_src2 = (const float*)d_in[9];
    const float* att_dst2 = (const float*)d_in[10];
    const float* bias2    = (const float*)d_in[11];
    float* out = (float*)d_out;

    const int N = in_sizes[0] / IN_DIM;      // 100000
    const int E = in_sizes[1] / 2;           // 1600000
    const int* src = eidx;
    const int* dst = eidx + E;
    const int nb = (N + BMASK) >> BSHIFT;    // 196 buckets

    char* w = (char*)d_ws;
    __hip_bfloat16* xb16  = (__hip_bfloat16*)w;  w += (size_t)N * IN_DIM * 2;   // 6.4 MB
    __hip_bfloat16* a     = (__hip_bfloat16*)w;  w += (size_t)N * 64 * 2;       // 12.8 MB
    __hip_bfloat16* h2b   = (__hip_bfloat16*)w;  w += (size_t)N * OUT_CH * 2;   // 12.8 MB
    __hip_bfloat16* W1t   = (__hip_bfloat16*)w;  w += IN_DIM * F1 * 2;
    __hip_bfloat16* W2t   = (__hip_bfloat16*)w;  w += F1 * OUT_CH * 2;
    float* wsd = (float*)w; w += 128 * 4;
    float* as1 = (float*)w; w += (size_t)N * 2 * 4;
    float* ad1 = (float*)w; w += (size_t)N * 2 * 4;
    float* as2 = (float*)w; w += (size_t)N * 4;
    float* ad2 = (float*)w; w += (size_t)N * 4;
    int* cnt    = (int*)w; w += (size_t)N * 4;
    int* rowptr = (int*)w; w += (size_t)N * 4;
    int* bfill  = (int*)w; w += 512 * 4;
    int* col    = (int*)w; w += (size_t)nb * CAP * 4;   // 8.0 MB (CAP-padded)
    unsigned int* bedge = (unsigned int*)w; w += (size_t)nb * CAP * 4;

    const int nchunk = (E + CHUNK - 1) / CHUNK;   // 391

    hipMemsetAsync(bfill, 0, 512 * 4, stream);
    k_bucket_pack<<<nchunk + 32, 256, 0, stream>>>(src, dst, E, nb, nchunk, bfill, bedge,
                                                   W1, W2, att_src1, att_dst1,
                                                   W1t, W2t, wsd);
    k_csr_att1<<<nb + (N + 255) / 256, 256, 0, stream>>>(bedge, bfill, N, nb,
                                                         cnt, rowptr, col,
                                                         x, wsd, xb16,
                                                         (float2*)as1, (float2*)ad1);
    k_agg1x<<<(N + 15) / 16, 256, 0, stream>>>(xb16, (const float2*)as1, (const float2*)ad1,
                                               rowptr, cnt, col, a, N);
    k_ln1node2<<<(N + 63) / 64, 256, 0, stream>>>(a, W1t, bias1, gamma, beta,
                                                  W2t, att_src2, att_dst2,
                                                  h2b, as2, ad2, N);
    k_agg2<<<(N + 15) / 16, 256, 0, stream>>>(h2b, as2, ad2,
                                              rowptr, cnt, col, bias2, out, N);
}

// Round 7
// 225.785 us; speedup vs baseline: 1.0884x; 1.0023x over previous
//
#include <hip/hip_runtime.h>
#include <hip/hip_bf16.h>
#include <hip/hip_fp16.h>

#define IN_DIM 32
#define HID 64
#define H1 2
#define F1 (H1 * HID)   // 128
#define OUT_CH 64
#define NEG_SLOPE 0.2f
#define LN_EPS 1e-5f

#define BSHIFT 9                     // 512 nodes per bucket
#define BMASK ((1 << BSHIFT) - 1)
#define CHUNK 4096                   // edges per block in bucketing pass
#define CAP 10240                    // fixed bucket capacity (mean 8163 + 23 sigma)

typedef __attribute__((ext_vector_type(8))) short short8x;   // 8 bf16 = 4 VGPRs
typedef __attribute__((ext_vector_type(4))) float floatx4;   // MFMA accumulator
typedef __attribute__((ext_vector_type(2))) float floatx2;   // packed-math pair

__device__ __forceinline__ float leaky(float x) {
    return x > 0.f ? x : NEG_SLOPE * x;
}
__device__ __forceinline__ float bf2f(__hip_bfloat16 v) { return __bfloat162float(v); }
__device__ __forceinline__ short f2bs(float v) {
    __hip_bfloat16 t = __float2bfloat16(v);
    return *reinterpret_cast<short*>(&t);
}
__device__ __forceinline__ unsigned pack_bf16x2(float lo, float hi) {
    unsigned ul = (unsigned)(unsigned short)f2bs(lo);
    unsigned uh = (unsigned)(unsigned short)f2bs(hi);
    return (uh << 16) | ul;
}
__device__ __forceinline__ float bfu_lo(unsigned u) { return __uint_as_float(u << 16); }
__device__ __forceinline__ float bfu_hi(unsigned u) { return __uint_as_float(u & 0xffff0000u); }
// packed fma on a float2 pair: c += a * b (one VOP3P instruction; r1-verified)
__device__ __forceinline__ void pk_fma(floatx2& c, floatx2 a, floatx2 b) {
    asm("v_pk_fma_f32 %0, %1, %2, %0" : "+v"(c) : "v"(a), "v"(b));
}

// ---------------- fused: bucket scatter (fixed-cap) + weight pack ----------------
__global__ __launch_bounds__(256) void k_bucket_pack(const int* __restrict__ src,
                                                     const int* __restrict__ dst,
                                                     int E, int nb, int nchunk,
                                                     int* __restrict__ bfill,
                                                     unsigned int* __restrict__ bedge,
                                                     const float* __restrict__ W1,
                                                     const float* __restrict__ W2,
                                                     const float* __restrict__ att_s,
                                                     const float* __restrict__ att_d,
                                                     __hip_bfloat16* __restrict__ W1t,
                                                     __hip_bfloat16* __restrict__ W2t,
                                                     float* __restrict__ wsd) {
    int t = threadIdx.x;
    if ((int)blockIdx.x >= nchunk) {
        int idx = ((int)blockIdx.x - nchunk) * 256 + t;
        if (idx < IN_DIM * F1) {
            int ch = idx >> 5, k = idx & 31;
            W1t[idx] = __float2bfloat16(W1[k * F1 + ch]);
        }
        if (idx < F1 * OUT_CH) {
            int ch = idx >> 7, k = idx & 127;
            W2t[idx] = __float2bfloat16(W2[k * OUT_CH + ch]);
        }
        if (idx < 128) {
            int v = idx >> 5;              // 0: ws h0, 1: ws h1, 2: wd h0, 3: wd h1
            int k = idx & 31;
            const float* att = (v & 2) ? att_d : att_s;
            int h = v & 1;
            float s = 0.f;
#pragma unroll 8
            for (int c = 0; c < HID; c++)
                s = fmaf(W1[k * F1 + h * HID + c], att[h * HID + c], s);
            wsd[v * 32 + k] = s;
        }
        return;
    }
    __shared__ int h[512];
    __shared__ int gb[512];
    for (int i = t; i < nb; i += 256) h[i] = 0;
    __syncthreads();
    int base = blockIdx.x * CHUNK;
    unsigned int pk[16];
    int rk[16], bk[16];
#pragma unroll
    for (int j = 0; j < 16; j++) {
        int e = base + j * 256 + t;
        if (e < E) {
            int d = dst[e];
            int b = d >> BSHIFT;
            bk[j] = b;
            pk[j] = ((unsigned)src[e] << BSHIFT) | (unsigned)(d & BMASK);
            rk[j] = atomicAdd(&h[b], 1);
        } else bk[j] = -1;
    }
    __syncthreads();
    for (int i = t; i < nb; i += 256)
        gb[i] = h[i] ? atomicAdd(&bfill[i], h[i]) : 0;
    __syncthreads();
#pragma unroll
    for (int j = 0; j < 16; j++)
        if (bk[j] >= 0) {
            int pos = gb[bk[j]] + rk[j];
            if (pos < CAP) bedge[(size_t)bk[j] * CAP + pos] = pk[j];
        }
}

// ---------------- fused: per-bucket CSR build + per-node att1 ----------------
__global__ __launch_bounds__(256) void k_csr_att1(const unsigned int* __restrict__ bedge,
                                                  const int* __restrict__ bfill, int n, int nb,
                                                  int* __restrict__ cnt,
                                                  int* __restrict__ rowptr,
                                                  int* __restrict__ col,
                                                  const float* __restrict__ x,
                                                  const float* __restrict__ wsd,
                                                  __hip_bfloat16* __restrict__ xb16,
                                                  float2* __restrict__ as1,
                                                  float2* __restrict__ ad1) {
    int t = threadIdx.x;
    if ((int)blockIdx.x >= nb) {
        int node = ((int)blockIdx.x - nb) * 256 + t;
        if (node >= n) return;
        const float4* xp = (const float4*)(x + (size_t)node * IN_DIM);
        float4 xr[8];
#pragma unroll
        for (int i = 0; i < 8; i++) xr[i] = xp[i];
        const float* xf = (const float*)xr;
        short8x* xo = (short8x*)(xb16 + (size_t)node * IN_DIM);
#pragma unroll
        for (int i = 0; i < 4; i++) {
            short8x xb;
#pragma unroll
            for (int j = 0; j < 8; j++) xb[j] = f2bs(xf[i * 8 + j]);
            xo[i] = xb;
        }
        float d0 = 0.f, d1 = 0.f, d2 = 0.f, d3 = 0.f;
#pragma unroll
        for (int k = 0; k < 32; k++) {
            float xv = xf[k];
            d0 = fmaf(xv, wsd[k], d0);
            d1 = fmaf(xv, wsd[32 + k], d1);
            d2 = fmaf(xv, wsd[64 + k], d2);
            d3 = fmaf(xv, wsd[96 + k], d3);
        }
        as1[node] = make_float2(d0, d1);
        ad1[node] = make_float2(d2, d3);
        return;
    }
    int b = blockIdx.x;
    __shared__ int lcnt[512];
    __shared__ int lscan[256];
    int nbase = b << BSHIFT;
    lcnt[2 * t] = 0; lcnt[2 * t + 1] = 0;
    __syncthreads();
    int estart = b * CAP;
    int eend = estart + min(bfill[b], CAP);
    for (int e = estart + t; e < eend; e += 256)
        atomicAdd(&lcnt[bedge[e] & BMASK], 1);
    __syncthreads();
    int c0 = lcnt[2 * t], c1 = lcnt[2 * t + 1];
    int s = c0 + c1;
    lscan[t] = s;
    __syncthreads();
    for (int off = 1; off < 256; off <<= 1) {
        int u = (t >= off) ? lscan[t - off] : 0;
        __syncthreads();
        lscan[t] += u;
        __syncthreads();
    }
    int ex = lscan[t] - s;
    int node0 = nbase + 2 * t, node1 = node0 + 1;
    if (node0 < n) { cnt[node0] = c0; rowptr[node0] = estart + ex; }
    if (node1 < n) { cnt[node1] = c1; rowptr[node1] = estart + ex + c0; }
    __syncthreads();
    lcnt[2 * t] = ex;
    lcnt[2 * t + 1] = ex + c0;
    __syncthreads();
    for (int e = estart + t; e < eend; e += 256) {
        unsigned int p = bedge[e];
        int pos = estart + atomicAdd(&lcnt[p & BMASK], 1);
        col[pos] = (int)(p >> BSHIFT);
    }
}

// ---------------- Layer 1 aggregation: 8 nodes/wave, 8 lanes/node ----------------
// Group g=lane>>3 owns node blockIdx*32+wave*8+g; lane gl=lane&7 owns channels
// {4gl..4gl+3} of BOTH heads (uint2 gather = 8B; 8 lanes cover the 64B x-row).
// 8 independent per-node latency chains per wave; accumulators are {head0,head1}
// floatx2 pairs fed by v_pk_fma_f32 with the packed {w0,w1} multiplier.
// Chunk weight-sums reduced once per 8-edge chunk (3-step group butterfly).
__global__ __launch_bounds__(256) void k_agg1x(const __hip_bfloat16* __restrict__ xb16,
                                               const float2* __restrict__ as1p,
                                               const float2* __restrict__ ad1p,
                                               const int* __restrict__ rowptr,
                                               const int* __restrict__ cnt,
                                               const int* __restrict__ col,
                                               __hip_bfloat16* __restrict__ a, int n) {
    int wave = threadIdx.x >> 6;
    int lane = threadIdx.x & 63;
    int g = lane >> 3;          // node within wave (8)
    int gl = lane & 7;          // lane within group
    int node = blockIdx.x * 32 + wave * 8 + g;
    bool valid = node < n;
    int nc = valid ? node : 0;
    float2 adn = ad1p[nc];
    float2 asn = as1p[nc];
    const unsigned* xu = (const unsigned*)xb16;   // 16 bf16x2 words per row
    // self loop
    float w0 = __expf(leaky(asn.x + adn.x));
    float w1 = __expf(leaky(asn.y + adn.y));
    uint2 su = *(const uint2*)(xu + (size_t)nc * 16 + gl * 2);
    float s0 = bfu_lo(su.x), s1 = bfu_hi(su.x), s2 = bfu_lo(su.y), s3 = bfu_hi(su.y);
    floatx2 acc0 = {w0 * s0, w1 * s0};   // {head0,head1} @ ch 4gl
    floatx2 acc1 = {w0 * s1, w1 * s1};   // ch 4gl+1
    floatx2 acc2 = {w0 * s2, w1 * s2};   // ch 4gl+2
    floatx2 acc3 = {w0 * s3, w1 * s3};   // ch 4gl+3
    float ws0 = w0, ws1 = w1;
    int start = valid ? rowptr[nc] : 0;
    int deg = valid ? cnt[nc] : 0;
    // wave-uniform max degree over the 8 groups
    int mx = deg;
    mx = max(mx, __shfl_xor(mx, 8, 64));
    mx = max(mx, __shfl_xor(mx, 16, 64));
    mx = max(mx, __shfl_xor(mx, 32, 64));
    int gbase = g << 3;
    for (int base = 0; base < mx; base += 8) {
        int m = deg - base;
        int colv = 0; unsigned wvv = 0u;    // wvv=0 => zero contribution for pad slots
        float e0 = 0.f, e1 = 0.f;
        if (gl < m) {
            colv = col[start + base + gl];
            float2 as = as1p[colv];
            e0 = __expf(leaky(as.x + adn.x));
            e1 = __expf(leaky(as.y + adn.y));
            wvv = ((unsigned)__half_as_ushort(__float2half(e1)) << 16)
                | (unsigned)__half_as_ushort(__float2half(e0));
        }
        // chunk weight sums (butterfly within the 8-lane group)
        float r0 = e0, r1 = e1;
#pragma unroll
        for (int off = 1; off < 8; off <<= 1) {
            r0 += __shfl_xor(r0, off, 64);
            r1 += __shfl_xor(r1, off, 64);
        }
        ws0 += r0; ws1 += r1;
        int kend = min(8, mx - base);
        int k = 0;
        for (; k + 8 <= kend; k += 8) {
            int sx[8]; unsigned uw[8];
#pragma unroll
            for (int q = 0; q < 8; q++) {
                sx[q] = __shfl(colv, gbase + q);
                uw[q] = __shfl(wvv, gbase + q);
            }
            uint2 gu[8];
#pragma unroll
            for (int q = 0; q < 8; q++)
                gu[q] = *(const uint2*)(xu + (size_t)sx[q] * 16 + gl * 2);
#pragma unroll
            for (int q = 0; q < 8; q++) {
                float ww0 = __half2float(__ushort_as_half((unsigned short)(uw[q] & 0xffffu)));
                float ww1 = __half2float(__ushort_as_half((unsigned short)(uw[q] >> 16)));
                floatx2 wp = {ww0, ww1};
                floatx2 g0 = {bfu_lo(gu[q].x), bfu_lo(gu[q].x)};
                floatx2 g1 = {bfu_hi(gu[q].x), bfu_hi(gu[q].x)};
                floatx2 g2 = {bfu_lo(gu[q].y), bfu_lo(gu[q].y)};
                floatx2 g3 = {bfu_hi(gu[q].y), bfu_hi(gu[q].y)};
                pk_fma(acc0, wp, g0);
                pk_fma(acc1, wp, g1);
                pk_fma(acc2, wp, g2);
                pk_fma(acc3, wp, g3);
            }
        }
        for (; k < kend; k++) {
            int s = __shfl(colv, gbase + k);
            unsigned u = __shfl(wvv, gbase + k);
            uint2 u2 = *(const uint2*)(xu + (size_t)s * 16 + gl * 2);
            float ww0 = __half2float(__ushort_as_half((unsigned short)(u & 0xffffu)));
            float ww1 = __half2float(__ushort_as_half((unsigned short)(u >> 16)));
            floatx2 wp = {ww0, ww1};
            floatx2 g0 = {bfu_lo(u2.x), bfu_lo(u2.x)};
            floatx2 g1 = {bfu_hi(u2.x), bfu_hi(u2.x)};
            floatx2 g2 = {bfu_lo(u2.y), bfu_lo(u2.y)};
            floatx2 g3 = {bfu_hi(u2.y), bfu_hi(u2.y)};
            pk_fma(acc0, wp, g0);
            pk_fma(acc1, wp, g1);
            pk_fma(acc2, wp, g2);
            pk_fma(acc3, wp, g3);
        }
    }
    if (valid) {
        float inv0 = 1.f / (ws0 + 1e-16f);
        float inv1 = 1.f / (ws1 + 1e-16f);
        // head0 ch {4gl..4gl+3} then head1 ch {4gl..4gl+3} (a row: [h0 ch0-31|h1 ch0-31])
        uint2 o0, o1;
        o0.x = pack_bf16x2(acc0.x * inv0, acc1.x * inv0);
        o0.y = pack_bf16x2(acc2.x * inv0, acc3.x * inv0);
        o1.x = pack_bf16x2(acc0.y * inv1, acc1.y * inv1);
        o1.y = pack_bf16x2(acc2.y * inv1, acc3.y * inv1);
        *(uint2*)(a + (size_t)node * 64 + 4 * gl) = o0;
        *(uint2*)(a + (size_t)node * 64 + 32 + 4 * gl) = o1;
    }
}

// ---------------- fused: a @ W1 + LN + ReLU -> LDS -> @ W2 + att coefs ----------------
__global__ __launch_bounds__(256) void k_ln1node2(const __hip_bfloat16* __restrict__ a,
                                                  const __hip_bfloat16* __restrict__ W1t,
                                                  const float* __restrict__ bias1,
                                                  const float* __restrict__ gamma,
                                                  const float* __restrict__ beta,
                                                  const __hip_bfloat16* __restrict__ W2t,
                                                  const float* __restrict__ att_s2,
                                                  const float* __restrict__ att_d2,
                                                  __hip_bfloat16* __restrict__ h2b,
                                                  float* __restrict__ as2,
                                                  float* __restrict__ ad2, int n) {
    __shared__ __hip_bfloat16 hs[64][136];   // 64 nodes x 128 ch (+8 pad), 17.4 KB
    int wave = threadIdx.x >> 6;
    int lane = threadIdx.x & 63;
    int row16 = lane & 15;
    int quad = lane >> 4;
    int node0 = blockIdx.x * 64 + wave * 16;

    // ---- phase 1: ln1 ----
    {
        short8x bfr[8];
#pragma unroll
        for (int nt = 0; nt < 8; nt++)
            bfr[nt] = *(const short8x*)(W1t + (nt * 16 + row16) * IN_DIM + quad * 8);

        int arow = node0 + row16;
        if (arow >= n) arow = n - 1;
        const __hip_bfloat16* ap = a + (size_t)arow * 64 + quad * 8;
        short8x af0 = *(const short8x*)ap;          // head0 channels (k 0..31)
        short8x af1 = *(const short8x*)(ap + 32);   // head1 channels (k 32..63)

        floatx4 acc[8];
#pragma unroll
        for (int nt = 0; nt < 8; nt++) acc[nt] = (floatx4){0.f, 0.f, 0.f, 0.f};
#pragma unroll
        for (int nt = 0; nt < 8; nt++)
            acc[nt] = __builtin_amdgcn_mfma_f32_16x16x32_bf16(nt < 4 ? af0 : af1, bfr[nt],
                                                              acc[nt], 0, 0, 0);

        float bv[8], gv[8], btv[8];
#pragma unroll
        for (int nt = 0; nt < 8; nt++) {
            int ch = nt * 16 + row16;
            bv[nt] = bias1[ch];
            gv[nt] = gamma[ch];
            btv[nt] = beta[ch];
        }
#pragma unroll
        for (int rr = 0; rr < 4; rr++) {
            int node = node0 + quad * 4 + rr;
            float v[8];
            float sum = 0.f, sq = 0.f;
#pragma unroll
            for (int nt = 0; nt < 8; nt++) {
                v[nt] = acc[nt][rr] + bv[nt];
                sum += v[nt];
                sq += v[nt] * v[nt];
            }
#pragma unroll
            for (int off = 1; off < 16; off <<= 1) {
                sum += __shfl_xor(sum, off, 64);
                sq += __shfl_xor(sq, off, 64);
            }
            float mu = sum * (1.f / 128.f);
            float var = sq * (1.f / 128.f) - mu * mu;
            float r = rsqrtf(var + LN_EPS);
            if (node < n) {
                int lr = wave * 16 + quad * 4 + rr;
#pragma unroll
                for (int nt = 0; nt < 8; nt++) {
                    float o = (v[nt] - mu) * r * gv[nt] + btv[nt];
                    hs[lr][nt * 16 + row16] = __float2bfloat16(fmaxf(o, 0.f));
                }
            }
        }
    }
    __syncthreads();

    // ---- phase 2: node2 ----
    short8x bfr2[4][4];
#pragma unroll
    for (int nt = 0; nt < 4; nt++) {
        const __hip_bfloat16* wrow = W2t + (nt * 16 + row16) * F1 + quad * 8;
#pragma unroll
        for (int kc = 0; kc < 4; kc++)
            bfr2[kc][nt] = *(const short8x*)(wrow + kc * 32);
    }

    floatx4 acc2[4];
#pragma unroll
    for (int nt = 0; nt < 4; nt++) acc2[nt] = (floatx4){0.f, 0.f, 0.f, 0.f};

    int lrow = wave * 16 + row16;   // rows beyond n hold garbage; outputs are guarded
#pragma unroll
    for (int kc = 0; kc < 4; kc++) {
        short8x af = *(const short8x*)&hs[lrow][quad * 8 + kc * 32];
#pragma unroll
        for (int nt = 0; nt < 4; nt++)
            acc2[nt] = __builtin_amdgcn_mfma_f32_16x16x32_bf16(af, bfr2[kc][nt], acc2[nt],
                                                               0, 0, 0);
    }

    float asv[4], adv[4];
#pragma unroll
    for (int nt = 0; nt < 4; nt++) {
        asv[nt] = att_s2[nt * 16 + row16];
        adv[nt] = att_d2[nt * 16 + row16];
    }
#pragma unroll
    for (int rr = 0; rr < 4; rr++) {
        int node = node0 + quad * 4 + rr;
        float ps = 0.f, pd = 0.f;
#pragma unroll
        for (int nt = 0; nt < 4; nt++) {
            float v = acc2[nt][rr];
            if (node < n) h2b[(size_t)node * OUT_CH + nt * 16 + row16] = __float2bfloat16(v);
            ps = fmaf(v, asv[nt], ps);
            pd = fmaf(v, adv[nt], pd);
        }
#pragma unroll
        for (int off = 1; off < 16; off <<= 1) {
            ps += __shfl_xor(ps, off, 64);
            pd += __shfl_xor(pd, off, 64);
        }
        if (row16 == 0 && node < n) { as2[node] = ps; ad2[node] = pd; }
    }
}

// ---------------- Layer 2 aggregation: 8 nodes/wave, 8 lanes/node ----------------
// Group g=lane>>3 owns node blockIdx*32+wave*8+g; lane gl=lane&7 owns channels
// {8gl..8gl+7} (uint4 gather = 16B; 8 lanes cover the 128B h2 row). 8 independent
// per-node latency chains per wave; 4-deep gather batches keep VGPR < 64.
// Chunk weight-sum reduced once per 8-edge chunk; epilogue has no cross-lane
// reduce (two coalesced float4 stores per lane).
__global__ __launch_bounds__(256) void k_agg2(const __hip_bfloat16* __restrict__ h2b,
                                              const float* __restrict__ as2,
                                              const float* __restrict__ ad2,
                                              const int* __restrict__ rowptr,
                                              const int* __restrict__ cnt,
                                              const int* __restrict__ col,
                                              const float* __restrict__ bias2,
                                              float* __restrict__ out, int n) {
    int wave = threadIdx.x >> 6;
    int lane = threadIdx.x & 63;
    int g = lane >> 3;          // node within wave (8)
    int gl = lane & 7;          // lane within group: ch 8gl..8gl+7
    int node = blockIdx.x * 32 + wave * 8 + g;
    bool valid = node < n;
    int nc = valid ? node : 0;
    const unsigned* h2u = (const unsigned*)h2b;   // 32 bf16x2 words per row
    float adn = ad2[nc];
    float wself = __expf(leaky(as2[nc] + adn));
    // self loop
    uint4 su = *(const uint4*)(h2u + (size_t)nc * 32 + gl * 4);
    floatx2 acc0 = {wself * bfu_lo(su.x), wself * bfu_hi(su.x)};   // ch 8gl+0,1
    floatx2 acc1 = {wself * bfu_lo(su.y), wself * bfu_hi(su.y)};   // ch 8gl+2,3
    floatx2 acc2 = {wself * bfu_lo(su.z), wself * bfu_hi(su.z)};   // ch 8gl+4,5
    floatx2 acc3 = {wself * bfu_lo(su.w), wself * bfu_hi(su.w)};   // ch 8gl+6,7
    float wsum = wself;
    int start = valid ? rowptr[nc] : 0;
    int deg = valid ? cnt[nc] : 0;
    // wave-uniform max degree over the 8 groups
    int mx = deg;
    mx = max(mx, __shfl_xor(mx, 8, 64));
    mx = max(mx, __shfl_xor(mx, 16, 64));
    mx = max(mx, __shfl_xor(mx, 32, 64));
    int gbase = g << 3;
    for (int base = 0; base < mx; base += 8) {
        int m = deg - base;
        int colv = 0; float wvv = 0.f;      // wvv=0 => zero contribution for pad slots
        if (gl < m) {
            colv = col[start + base + gl];
            wvv = __expf(leaky(as2[colv] + adn));
        }
        // chunk weight sum (butterfly within the 8-lane group)
        float r = wvv;
#pragma unroll
        for (int off = 1; off < 8; off <<= 1) r += __shfl_xor(r, off, 64);
        wsum += r;
        int kend = min(8, mx - base);
        int k = 0;
        for (; k + 4 <= kend; k += 4) {
            int sx[4]; float wx[4];
#pragma unroll
            for (int q = 0; q < 4; q++) {
                sx[q] = __shfl(colv, gbase + k + q);
                wx[q] = __shfl(wvv, gbase + k + q);
            }
            uint4 gu[4];
#pragma unroll
            for (int q = 0; q < 4; q++)
                gu[q] = *(const uint4*)(h2u + (size_t)sx[q] * 32 + gl * 4);
#pragma unroll
            for (int q = 0; q < 4; q++) {
                floatx2 wp = {wx[q], wx[q]};
                floatx2 g0 = {bfu_lo(gu[q].x), bfu_hi(gu[q].x)};
                floatx2 g1 = {bfu_lo(gu[q].y), bfu_hi(gu[q].y)};
                floatx2 g2 = {bfu_lo(gu[q].z), bfu_hi(gu[q].z)};
                floatx2 g3 = {bfu_lo(gu[q].w), bfu_hi(gu[q].w)};
                pk_fma(acc0, wp, g0);
                pk_fma(acc1, wp, g1);
                pk_fma(acc2, wp, g2);
                pk_fma(acc3, wp, g3);
            }
        }
        for (; k < kend; k++) {
            int s = __shfl(colv, gbase + k);
            float wk = __shfl(wvv, gbase + k);
            uint4 u4 = *(const uint4*)(h2u + (size_t)s * 32 + gl * 4);
            floatx2 wp = {wk, wk};
            floatx2 g0 = {bfu_lo(u4.x), bfu_hi(u4.x)};
            floatx2 g1 = {bfu_lo(u4.y), bfu_hi(u4.y)};
            floatx2 g2 = {bfu_lo(u4.z), bfu_hi(u4.z)};
            floatx2 g3 = {bfu_lo(u4.w), bfu_hi(u4.w)};
            pk_fma(acc0, wp, g0);
            pk_fma(acc1, wp, g1);
            pk_fma(acc2, wp, g2);
            pk_fma(acc3, wp, g3);
        }
    }
    if (valid) {
        float inv = 1.f / (wsum + 1e-16f);
        const float4* bp = (const float4*)bias2;
        float4 bv0 = bp[gl * 2], bv1 = bp[gl * 2 + 1];
        float4 ov0, ov1;
        ov0.x = acc0.x * inv + bv0.x;
        ov0.y = acc0.y * inv + bv0.y;
        ov0.z = acc1.x * inv + bv0.z;
        ov0.w = acc1.y * inv + bv0.w;
        ov1.x = acc2.x * inv + bv1.x;
        ov1.y = acc2.y * inv + bv1.y;
        ov1.z = acc3.x * inv + bv1.z;
        ov1.w = acc3.y * inv + bv1.w;
        float4* op = (float4*)out + (size_t)node * 16 + gl * 2;
        op[0] = ov0;
        op[1] = ov1;
    }
}

extern "C" void kernel_launch(void* const* d_in, const int* in_sizes, int n_in,
                              void* d_out, int out_size, void* d_ws, size_t ws_size,
                              hipStream_t stream) {
    const float* x        = (const float*)d_in[0];
    const int*   eidx     = (const int*)d_in[1];
    const float* W1       = (const float*)d_in[2];
    const float* att_src1 = (const float*)d_in[3];
    const float* att_dst1 = (const float*)d_in[4];
    const float* bias1    = (const float*)d_in[5];
    const float* gamma    = (const float*)d_in[6];
    const float* beta     = (const float*)d_in[7];
    const float* W2       = (const float*)d_in[8];
    const float* att_src2 = (const float*)d_in[9];
    const float* att_dst2 = (const float*)d_in[10];
    const float* bias2    = (const float*)d_in[11];
    float* out = (float*)d_out;

    const int N = in_sizes[0] / IN_DIM;      // 100000
    const int E = in_sizes[1] / 2;           // 1600000
    const int* src = eidx;
    const int* dst = eidx + E;
    const int nb = (N + BMASK) >> BSHIFT;    // 196 buckets

    char* w = (char*)d_ws;
    __hip_bfloat16* xb16  = (__hip_bfloat16*)w;  w += (size_t)N * IN_DIM * 2;   // 6.4 MB
    __hip_bfloat16* a     = (__hip_bfloat16*)w;  w += (size_t)N * 64 * 2;       // 12.8 MB
    __hip_bfloat16* h2b   = (__hip_bfloat16*)w;  w += (size_t)N * OUT_CH * 2;   // 12.8 MB
    __hip_bfloat16* W1t   = (__hip_bfloat16*)w;  w += IN_DIM * F1 * 2;
    __hip_bfloat16* W2t   = (__hip_bfloat16*)w;  w += F1 * OUT_CH * 2;
    float* wsd = (float*)w; w += 128 * 4;
    float* as1 = (float*)w; w += (size_t)N * 2 * 4;
    float* ad1 = (float*)w; w += (size_t)N * 2 * 4;
    float* as2 = (float*)w; w += (size_t)N * 4;
    float* ad2 = (float*)w; w += (size_t)N * 4;
    int* cnt    = (int*)w; w += (size_t)N * 4;
    int* rowptr = (int*)w; w += (size_t)N * 4;
    int* bfill  = (int*)w; w += 512 * 4;
    int* col    = (int*)w; w += (size_t)nb * CAP * 4;   // 8.0 MB (CAP-padded)
    unsigned int* bedge = (unsigned int*)w; w += (size_t)nb * CAP * 4;

    const int nchunk = (E + CHUNK - 1) / CHUNK;   // 391

    hipMemsetAsync(bfill, 0, 512 * 4, stream);
    k_bucket_pack<<<nchunk + 32, 256, 0, stream>>>(src, dst, E, nb, nchunk, bfill, bedge,
                                                   W1, W2, att_src1, att_dst1,
                                                   W1t, W2t, wsd);
    k_csr_att1<<<nb + (N + 255) / 256, 256, 0, stream>>>(bedge, bfill, N, nb,
                                                         cnt, rowptr, col,
                                                         x, wsd, xb16,
                                                         (float2*)as1, (float2*)ad1);
    k_agg1x<<<(N + 31) / 32, 256, 0, stream>>>(xb16, (const float2*)as1, (const float2*)ad1,
                                               rowptr, cnt, col, a, N);
    k_ln1node2<<<(N + 63) / 64, 256, 0, stream>>>(a, W1t, bias1, gamma, beta,
                                                  W2t, att_src2, att_dst2,
                                                  h2b, as2, ad2, N);
    k_agg2<<<(N + 31) / 32, 256, 0, stream>>>(h2b, as2, ad2,
                                              rowptr, cnt, col, bias2, out, N);
}